// Round 9
// baseline (486.033 us; speedup 1.0000x reference)
//
#include <hip/hip_runtime.h>
#include <cstdint>
#include <cstddef>

#define B_    32
#define S_    2048
#define D_    64
#define QBLK  16            // q rows per block
#define SLICE 264           // padded per-wave P slice stride (shorts): 256 + 8

typedef __attribute__((ext_vector_type(8))) short short8_t;  // 8 bf16 (4 VGPRs)
typedef __attribute__((ext_vector_type(4))) float f32x4;     // MFMA acc
typedef __attribute__((ext_vector_type(2))) unsigned u32x2;
typedef __attribute__((ext_vector_type(2))) float f32x2;

__device__ __forceinline__ short f2bf(float f) {
  union { float f; unsigned u; } x; x.f = f;
  unsigned u = x.u;
  u += 0x7fffu + ((u >> 16) & 1u);   // round-to-nearest-even
  return (short)(u >> 16);
}
__device__ __forceinline__ float bf2f(unsigned s) {
  union { unsigned u; float f; } x;
  x.u = (s & 0xffffu) << 16;
  return x.f;
}

// 8B store with sc1 cache policy: write past L2 (keeps K/Vt L2-resident),
// without the nt retention hint (probe: is nt the 2.5 TB/s culprit?).
__device__ __forceinline__ void store_sc1_b64(void* addr, u32x2 v) {
  asm volatile("global_store_dwordx2 %0, %1, off sc1"
               :: "v"(addr), "v"(v) : "memory");
}

// ---- fp32 -> bf16 elementwise (for K) ----
__global__ void convert_bf16_kernel(const float* __restrict__ in,
                                    short* __restrict__ out, int n4) {
  int i = blockIdx.x * blockDim.x + threadIdx.x;
  if (i >= n4) return;
  f32x4 f = ((const f32x4*)in)[i];
  short4 o;
  o.x = f2bf(f[0]); o.y = f2bf(f[1]); o.z = f2bf(f[2]); o.w = f2bf(f[3]);
  ((short4*)out)[i] = o;
}

// ---- V [B][S][D] fp32 -> Vt [B][D][S] bf16 (so PV B-frags are contiguous) ----
__global__ void transpose_v_kernel(const float* __restrict__ v,
                                   short* __restrict__ vt) {
  __shared__ float t[64][65];
  int b   = blockIdx.x >> 5;
  int st  = blockIdx.x & 31;
  int tid = threadIdx.x;
  const float* src = v + ((size_t)(b * S_ + st * 64)) * D_;
#pragma unroll
  for (int p = 0; p < 4; ++p) {
    int r = p * 16 + (tid >> 4);
    int c = (tid & 15) * 4;
    f32x4 f = *(const f32x4*)(src + (size_t)r * D_ + c);
    t[r][c] = f[0]; t[r][c+1] = f[1]; t[r][c+2] = f[2]; t[r][c+3] = f[3];
  }
  __syncthreads();
#pragma unroll
  for (int p = 0; p < 8; ++p) {
    int d  = p * 8 + (tid >> 5);
    int si = (tid & 31) * 2;
    unsigned lo = (unsigned short)f2bf(t[si][d]);
    unsigned hi = (unsigned short)f2bf(t[si + 1][d]);
    *(unsigned*)(vt + ((size_t)(b * D_ + d)) * S_ + st * 64 + si) = lo | (hi << 16);
  }
}

// ---- copy-shaped finalize: attn = P(bf16) * rinv[row], plain load/store ----
// m13's float4-copy pattern (6.29 TB/s proven): the plain-stream rate probe.
__global__ __launch_bounds__(256)
void expand_kernel(const unsigned* __restrict__ P, const float* __restrict__ rinv,
                   float* __restrict__ attn, long n4) {
  long i      = (long)blockIdx.x * blockDim.x + threadIdx.x;
  long stride = (long)gridDim.x * blockDim.x;
  for (; i < n4; i += stride) {
    u32x2 pk = *((const u32x2*)P + i);
    float rl = rinv[i >> 9];          // 512 4-float groups per row; wave-uniform
    f32x4 o;
    o[0] = bf2f(pk[0])       * rl;
    o[1] = bf2f(pk[0] >> 16) * rl;
    o[2] = bf2f(pk[1])       * rl;
    o[3] = bf2f(pk[1] >> 16) * rl;
    *((f32x4*)attn + i) = o;
  }
}

// ==== main fused kernel (wave-private, 2 barriers) ====
// SPLIT=1: P (unnormalized bf16) -> ws via sc1 stores (issued BEFORE PV so
//          they drain under the MFMAs); rinv -> ws; no attn stores.
// SPLIT=0: round-8 behavior (fused NT attn stores) — fallback.
template <bool WS, bool SPLIT>
__global__ __launch_bounds__(512, 4)
void attn_kernel(const float* __restrict__ q, const float* __restrict__ k,
                 const float* __restrict__ v, const short* __restrict__ Kb,
                 const short* __restrict__ Vt, float* __restrict__ out,
                 float* __restrict__ attn, short* __restrict__ Pws,
                 float* __restrict__ rinv_ws) {
  __shared__ short P_s[8][QBLK][SLICE];      // 67584 B (wave-private slices)
  __shared__ float rs[QBLK];
  __shared__ float Obuf[QBLK][66];

  const int tid  = threadIdx.x;
  const int lane = tid & 63;
  const int wv   = tid >> 6;
  const int lr   = lane & 15;
  const int lq   = lane >> 4;

  const int nwg  = gridDim.x;
  const int per  = nwg >> 3;
  const int bid0 = blockIdx.x;
  const int bid  = (bid0 & 7) * per + (bid0 >> 3);

  const int b     = bid >> 7;
  const int qbase = (bid & 127) * QBLK;
  const int wcol  = wv * 256;

  if (tid < QBLK) rs[tid] = 0.f;
  for (int i = tid; i < QBLK * 66; i += 512) ((float*)Obuf)[i] = 0.f;
  __syncthreads();                           // barrier 0

  short8_t qf[2];
  {
    const float* qp = q + ((size_t)(b * S_ + qbase + lr)) * D_ + lq * 8;
#pragma unroll
    for (int kp = 0; kp < 2; ++kp) {
      f32x4 f0 = *(const f32x4*)(qp + kp * 32);
      f32x4 f1 = *(const f32x4*)(qp + kp * 32 + 4);
      short8_t a;
      a[0] = f2bf(f0[0]); a[1] = f2bf(f0[1]); a[2] = f2bf(f0[2]); a[3] = f2bf(f0[3]);
      a[4] = f2bf(f1[0]); a[5] = f2bf(f1[1]); a[6] = f2bf(f1[2]); a[7] = f2bf(f1[3]);
      qf[kp] = a;
    }
  }

  // ---------- Phase 1: S^T = K Q^T ----------
  f32x4 acc[16];
#pragma unroll
  for (int ct = 0; ct < 16; ++ct) acc[ct] = (f32x4){0.f, 0.f, 0.f, 0.f};

#pragma unroll
  for (int ct = 0; ct < 16; ++ct) {
    int n = wcol + ct * 16 + lr;
    short8_t b0, b1;
    if constexpr (WS) {
      const short* kr = Kb + ((size_t)(b * S_ + n)) * D_ + lq * 8;
      b0 = *(const short8_t*)(kr);
      b1 = *(const short8_t*)(kr + 32);
    } else {
      const float* kr = k + ((size_t)(b * S_ + n)) * D_ + lq * 8;
      f32x4 f0 = *(const f32x4*)(kr);
      f32x4 f1 = *(const f32x4*)(kr + 4);
      f32x4 f2 = *(const f32x4*)(kr + 32);
      f32x4 f3 = *(const f32x4*)(kr + 36);
      b0[0]=f2bf(f0[0]); b0[1]=f2bf(f0[1]); b0[2]=f2bf(f0[2]); b0[3]=f2bf(f0[3]);
      b0[4]=f2bf(f1[0]); b0[5]=f2bf(f1[1]); b0[6]=f2bf(f1[2]); b0[7]=f2bf(f1[3]);
      b1[0]=f2bf(f2[0]); b1[1]=f2bf(f2[1]); b1[2]=f2bf(f2[2]); b1[3]=f2bf(f2[3]);
      b1[4]=f2bf(f3[0]); b1[5]=f2bf(f3[1]); b1[6]=f2bf(f3[2]); b1[7]=f2bf(f3[3]);
    }
    acc[ct] = __builtin_amdgcn_mfma_f32_16x16x32_bf16(b0, qf[0], acc[ct], 0, 0, 0);
    acc[ct] = __builtin_amdgcn_mfma_f32_16x16x32_bf16(b1, qf[1], acc[ct], 0, 0, 0);
  }

  // ---------- Phase 2: exp (no max-sub) + stage P + rowsum ----------
  float s0 = 0.f, s1 = 0.f, s2 = 0.f, s3 = 0.f;
#pragma unroll
  for (int ct = 0; ct < 16; ++ct) {
    float p0 = __expf(acc[ct][0] * 0.125f);
    float p1 = __expf(acc[ct][1] * 0.125f);
    float p2 = __expf(acc[ct][2] * 0.125f);
    float p3 = __expf(acc[ct][3] * 0.125f);
    s0 += p0; s1 += p1; s2 += p2; s3 += p3;
    u32x2 pk;
    pk[0] = (unsigned)(unsigned short)f2bf(p0) |
            ((unsigned)(unsigned short)f2bf(p1) << 16);
    pk[1] = (unsigned)(unsigned short)f2bf(p2) |
            ((unsigned)(unsigned short)f2bf(p3) << 16);
    *(u32x2*)&P_s[wv][lr][ct * 16 + lq * 4] = pk;
  }
  float s = (s0 + s1) + (s2 + s3);
  s += __shfl_xor(s, 16);
  s += __shfl_xor(s, 32);
  if (lane < 16) atomicAdd(&rs[lr], s);

  // ---------- Phase 2.5 (SPLIT): stream P rows to ws via sc1 stores ----------
  // Dense 512B/instr from private slice; issued BEFORE PV so the HBM drain
  // overlaps the MFMA phase. Unnormalized (expand applies rinv).
  if constexpr (SPLIT) {
#pragma unroll
    for (int r = 0; r < QBLK; ++r) {
      u32x2 pk = *(const u32x2*)&P_s[wv][r][lane * 4];
      store_sc1_b64(Pws + ((size_t)(b * S_ + qbase + r)) * S_ + wcol + lane * 4, pk);
    }
  }

  // ---------- Phase 3: PV over own k-slice ----------
  f32x4 oacc[4];
#pragma unroll
  for (int dt = 0; dt < 4; ++dt) oacc[dt] = (f32x4){0.f, 0.f, 0.f, 0.f};

#pragma unroll
  for (int ks = 0; ks < 8; ++ks) {
    short8_t pa = *(const short8_t*)&P_s[wv][lr][ks * 32 + lq * 8];
#pragma unroll
    for (int dt = 0; dt < 4; ++dt) {
      short8_t vb;
      if constexpr (WS) {
        vb = *(const short8_t*)(Vt + ((size_t)(b * D_ + dt * 16 + lr)) * S_
                                + wcol + ks * 32 + lq * 8);
      } else {
#pragma unroll
        for (int e = 0; e < 8; ++e)
          vb[e] = f2bf(v[((size_t)(b * S_ + wcol + ks * 32 + lq * 8 + e)) * D_
                         + dt * 16 + lr]);
      }
      oacc[dt] = __builtin_amdgcn_mfma_f32_16x16x32_bf16(pa, vb, oacc[dt], 0, 0, 0);
    }
  }
#pragma unroll
  for (int dt = 0; dt < 4; ++dt)
#pragma unroll
    for (int i = 0; i < 4; ++i)
      atomicAdd(&Obuf[lq * 4 + i][dt * 16 + lr], oacc[dt][i]);

  __syncthreads();                           // barrier 1

  // ---------- Phase 4a: out = Obuf * (1/rs); rinv -> ws ----------
  {
    const int qq = tid >> 5;
    const int d0 = (tid & 31) * 2;
    const float rlq = 1.f / rs[qq];
    f32x2 o;
    o[0] = Obuf[qq][d0]     * rlq;
    o[1] = Obuf[qq][d0 + 1] * rlq;
    *(f32x2*)(out + ((size_t)(b * S_ + qbase + qq)) * D_ + d0) = o;
  }
  if constexpr (SPLIT) {
    if (tid < QBLK) rinv_ws[b * S_ + qbase + tid] = 1.f / rs[tid];
  }

  // ---------- Phase 4b (fallback only): fused NT attn stores ----------
  if constexpr (!SPLIT) {
#pragma unroll
    for (int r = 0; r < QBLK; ++r) {
      const float rlr = 1.f / rs[r];
      u32x2 pk = *(const u32x2*)&P_s[wv][r][lane * 4];
      f32x4 o;
      o[0] = bf2f(pk[0])       * rlr;
      o[1] = bf2f(pk[0] >> 16) * rlr;
      o[2] = bf2f(pk[1])       * rlr;
      o[3] = bf2f(pk[1] >> 16) * rlr;
      __builtin_nontemporal_store(
          o, (f32x4*)(attn + ((size_t)b * S_ + qbase + r) * S_ + wcol + lane * 4));
    }
  }
}

extern "C" void kernel_launch(void* const* d_in, const int* in_sizes, int n_in,
                              void* d_out, int out_size, void* d_ws, size_t ws_size,
                              hipStream_t stream) {
  (void)in_sizes; (void)n_in; (void)out_size;
  const float* q = (const float*)d_in[0];
  const float* k = (const float*)d_in[1];
  const float* v = (const float*)d_in[2];
  float* out  = (float*)d_out;
  float* attn = out + (size_t)B_ * S_ * D_;

  const size_t nelem  = (size_t)B_ * S_ * D_;          // 4,194,304
  const size_t needKV = nelem * 2 * sizeof(short);     // Kb + Vt = 16 MB
  const size_t nRows  = (size_t)B_ * S_;               // 65536
  const size_t nP     = (size_t)B_ * S_ * S_;          // 134,217,728
  const size_t needAll = needKV + nRows * sizeof(float) + nP * sizeof(short);

  dim3 grid(B_ * (S_ / QBLK));                         // 4096 blocks
  if (d_ws != nullptr && ws_size >= needAll) {
    short* Kb   = (short*)d_ws;
    short* Vt   = Kb + nelem;
    float* rinv = (float*)(Vt + nelem);
    short* Pws  = (short*)(rinv + nRows);
    convert_bf16_kernel<<<(int)((nelem / 4 + 255) / 256), 256, 0, stream>>>(k, Kb, (int)(nelem / 4));
    transpose_v_kernel<<<B_ * (S_ / 64), 256, 0, stream>>>(v, Vt);
    attn_kernel<true, true><<<grid, 512, 0, stream>>>(q, k, v, Kb, Vt, out, attn, Pws, rinv);
    expand_kernel<<<2048, 256, 0, stream>>>((const unsigned*)Pws, rinv, attn, (long)(nP / 4));
  } else if (d_ws != nullptr && ws_size >= needKV) {
    short* Kb = (short*)d_ws;
    short* Vt = Kb + nelem;
    convert_bf16_kernel<<<(int)((nelem / 4 + 255) / 256), 256, 0, stream>>>(k, Kb, (int)(nelem / 4));
    transpose_v_kernel<<<B_ * (S_ / 64), 256, 0, stream>>>(v, Vt);
    attn_kernel<true, false><<<grid, 512, 0, stream>>>(q, k, v, Kb, Vt, out, attn, nullptr, nullptr);
  } else {
    attn_kernel<false, false><<<grid, 512, 0, stream>>>(q, k, v, nullptr, nullptr, out, attn, nullptr, nullptr);
  }
}